// Round 6
// baseline (608.209 us; speedup 1.0000x reference)
//
#include <hip/hip_runtime.h>

typedef unsigned short u16;
typedef unsigned int   u32;
typedef unsigned long long u64;

#define F 128
#define F3 384
#define TA 32          // atoms per MLP block
#define PAD 36         // padded LDS row (floats)

__device__ __forceinline__ float bf2f(u16 v) {
    union { u32 u; float f; } c; c.u = ((u32)v) << 16; return c.f;
}
__device__ __forceinline__ u16 f2bf(float f) {
    union { float fv; u32 u; } c; c.fv = f;
    u32 u = c.u;
    return (u16)((u + 0x7fffu + ((u >> 16) & 1u)) >> 16);   // round-nearest-even
}
__device__ __forceinline__ float u2f(u32 v) {
    union { u32 u; float f; } c; c.u = v; return c.f;
}
__device__ __forceinline__ u32 f2u(float v) {
    union { float f; u32 u; } c; c.f = v; return c.u;
}

// dtype-generic accessors: BF=true -> bf16 (u16) arrays, false -> f32 arrays
template<bool BF> __device__ __forceinline__ float LD(const void* p, size_t i) {
    return BF ? bf2f(((const u16*)p)[i]) : ((const float*)p)[i];
}
template<bool BF> __device__ __forceinline__ float2 LD2(const void* p, size_t i) {
    if (BF) {
        u32 v = *(const u32*)((const u16*)p + i);
        float2 r; r.x = bf2f((u16)(v & 0xffff)); r.y = bf2f((u16)(v >> 16)); return r;
    }
    return *(const float2*)((const float*)p + i);
}
template<bool BF> __device__ __forceinline__ void ST2(void* p, size_t i, float2 v) {
    if (BF) { *(u32*)((u16*)p + i) = ((u32)f2bf(v.y) << 16) | f2bf(v.x); }
    else    { *(float2*)((float*)p + i) = v; }
}
__device__ __forceinline__ float2 LD2bf(const u16* p, size_t i) {
    u32 v = *(const u32*)(p + i);
    float2 r; r.x = bf2f((u16)(v & 0xffff)); r.y = bf2f((u16)(v >> 16)); return r;
}
template<bool BF> __device__ __forceinline__ float4 LD4(const void* p, size_t i) {
    if (BF) {
        uint2 v = *(const uint2*)((const u16*)p + i);
        float4 r;
        r.x = bf2f((u16)(v.x & 0xffff)); r.y = bf2f((u16)(v.x >> 16));
        r.z = bf2f((u16)(v.y & 0xffff)); r.w = bf2f((u16)(v.y >> 16));
        return r;
    }
    return *(const float4*)((const float*)p + i);
}
// nontemporal variants (touch-once streams: Wij, out)
template<bool BF> __device__ __forceinline__ float2 NTLD2(const void* p, size_t i) {
    if (BF) {
        u32 v = __builtin_nontemporal_load((const u32*)((const u16*)p + i));
        float2 r; r.x = bf2f((u16)(v & 0xffff)); r.y = bf2f((u16)(v >> 16)); return r;
    } else {
        u64 v = __builtin_nontemporal_load((const u64*)((const float*)p + i));
        float2 r; r.x = u2f((u32)v); r.y = u2f((u32)(v >> 32)); return r;
    }
}
template<bool BF> __device__ __forceinline__ void NTST2(void* p, size_t i, float2 v) {
    if (BF) {
        u32 o = ((u32)f2bf(v.y) << 16) | f2bf(v.x);
        __builtin_nontemporal_store(o, (u32*)((u16*)p + i));
    } else {
        u64 o = ((u64)f2u(v.y) << 32) | f2u(v.x);
        __builtin_nontemporal_store(o, (u64*)((float*)p + i));
    }
}

// ---------------------------------------------------------------------------
// Dtype detector (proven): bf16 arrays have sane exponent fields at even u16
// indices; f32 arrays give ~20% hit-rate there.
// ---------------------------------------------------------------------------
__global__ __launch_bounds__(256) void detect_kernel(const void* q, int* flag) {
    __shared__ int cnt;
    if (threadIdx.x == 0) cnt = 0;
    __syncthreads();
    const u16* p = (const u16*)q;
    int c = 0;
    for (int i = threadIdx.x; i < 1024; i += 256) {
        u16 v = p[2 * i];
        int e = (v >> 7) & 0xFF;
        if (e >= 100 && e <= 150) c++;
    }
    atomicAdd(&cnt, c);
    __syncthreads();
    if (threadIdx.x == 0) *flag = (cnt > 512) ? 1 : 0;
}

// ---------------------------------------------------------------------------
// mu -> interleaved bf16 [A][128][4] = (c0,c1,c2,pad) per feature
// ---------------------------------------------------------------------------
template<bool BF>
__device__ void mu4_body(const void* mu, u16* dst, int n_atoms) {
    int a = blockIdx.x * 2 + (threadIdx.x >> 7);
    int f = threadIdx.x & 127;
    if (a >= n_atoms) return;
    float m0 = LD<BF>(mu, (size_t)a * F3 + f);
    float m1 = LD<BF>(mu, (size_t)a * F3 + 128 + f);
    float m2 = LD<BF>(mu, (size_t)a * F3 + 256 + f);
    uint2 o;
    o.x = ((u32)f2bf(m1) << 16) | f2bf(m0);
    o.y = f2bf(m2);
    *(uint2*)(dst + ((size_t)a * F + f) * 4) = o;
}
__global__ __launch_bounds__(256) void mu4_kernel(const void* mu, u16* dst,
                                                  int n_atoms, const int* flag) {
    if (*flag) mu4_body<true >(mu, dst, n_atoms);
    else       mu4_body<false>(mu, dst, n_atoms);
}

// ---------------------------------------------------------------------------
// Full MLP: h = silu(q@W1+b1) once, then 3 chunks -> interleaved xcf4
// [A][128][4] = (xq, xR, xm, pad) per feature.
// ---------------------------------------------------------------------------
template<bool BF>
__device__ void mlpfull_body(const void* q, const void* W1, const void* b1,
                             const void* W2, const void* b2,
                             u16* __restrict__ xcf4, int n_atoms)
{
    __shared__ float qT[F][PAD];
    __shared__ float hT[F][PAD];

    const int tid = threadIdx.x;
    const int a0  = blockIdx.x * TA;
    const int c4  = (tid & 31) * 4;
    const int r4  = (tid >> 5) * 4;

    for (int i = tid; i < TA * F / 8; i += 256) {
        int a = i >> 4, f0 = (i & 15) * 8;
        float4 v0, v1;
        if (a0 + a < n_atoms) {
            v0 = LD4<BF>(q, (size_t)(a0 + a) * F + f0);
            v1 = LD4<BF>(q, (size_t)(a0 + a) * F + f0 + 4);
        } else { v0 = v1 = make_float4(0, 0, 0, 0); }
        qT[f0 + 0][a] = v0.x; qT[f0 + 1][a] = v0.y; qT[f0 + 2][a] = v0.z; qT[f0 + 3][a] = v0.w;
        qT[f0 + 4][a] = v1.x; qT[f0 + 5][a] = v1.y; qT[f0 + 6][a] = v1.z; qT[f0 + 7][a] = v1.w;
    }
    __syncthreads();

    // phase 1: h = silu(q@W1 + b1)
    {
        float acc[4][4];
#pragma unroll
        for (int rr = 0; rr < 4; ++rr)
#pragma unroll
            for (int cc = 0; cc < 4; ++cc) acc[rr][cc] = 0.0f;

        for (int f = 0; f < F; ++f) {
            float4 qv = *(const float4*)&qT[f][r4];
            float4 w  = LD4<BF>(W1, (size_t)f * F + c4);
            float qa[4] = {qv.x, qv.y, qv.z, qv.w};
            float wa[4] = {w.x, w.y, w.z, w.w};
#pragma unroll
            for (int rr = 0; rr < 4; ++rr)
#pragma unroll
                for (int cc = 0; cc < 4; ++cc)
                    acc[rr][cc] += qa[rr] * wa[cc];
        }
#pragma unroll
        for (int cc = 0; cc < 4; ++cc) {
            float bb = LD<BF>(b1, c4 + cc);
#pragma unroll
            for (int rr = 0; rr < 4; ++rr) {
                float h = acc[rr][cc] + bb;
                hT[c4 + cc][r4 + rr] = h / (1.0f + __expf(-h));
            }
        }
    }
    __syncthreads();

    // phase 2: all 3 chunks, register-staged, then interleaved coalesced store
    float xout[4][4][3];   // [rr][feat cc][chunk cb] — all indices compile-time
#pragma unroll
    for (int cb = 0; cb < 3; ++cb) {
        float acc[4][4];
#pragma unroll
        for (int rr = 0; rr < 4; ++rr)
#pragma unroll
            for (int cc = 0; cc < 4; ++cc) acc[rr][cc] = 0.0f;

        for (int f = 0; f < F; ++f) {
            float4 hv = *(const float4*)&hT[f][r4];
            float4 w  = LD4<BF>(W2, (size_t)f * F3 + cb * F + c4);
            float ha[4] = {hv.x, hv.y, hv.z, hv.w};
            float wa[4] = {w.x, w.y, w.z, w.w};
#pragma unroll
            for (int rr = 0; rr < 4; ++rr)
#pragma unroll
                for (int cc = 0; cc < 4; ++cc)
                    acc[rr][cc] += ha[rr] * wa[cc];
        }
#pragma unroll
        for (int cc = 0; cc < 4; ++cc) {
            float bb = LD<BF>(b2, cb * F + c4 + cc);
#pragma unroll
            for (int rr = 0; rr < 4; ++rr)
                xout[rr][cc][cb] = acc[rr][cc] + bb;
        }
    }
#pragma unroll
    for (int rr = 0; rr < 4; ++rr) {
        int ga = a0 + r4 + rr;
        if (ga < n_atoms) {
            uint4 o1, o2;
            o1.x = ((u32)f2bf(xout[rr][0][1]) << 16) | f2bf(xout[rr][0][0]);
            o1.y = f2bf(xout[rr][0][2]);
            o1.z = ((u32)f2bf(xout[rr][1][1]) << 16) | f2bf(xout[rr][1][0]);
            o1.w = f2bf(xout[rr][1][2]);
            o2.x = ((u32)f2bf(xout[rr][2][1]) << 16) | f2bf(xout[rr][2][0]);
            o2.y = f2bf(xout[rr][2][2]);
            o2.z = ((u32)f2bf(xout[rr][3][1]) << 16) | f2bf(xout[rr][3][0]);
            o2.w = f2bf(xout[rr][3][2]);
            *(uint4*)(xcf4 + ((size_t)ga * F + c4) * 4)     = o1;
            *(uint4*)(xcf4 + ((size_t)ga * F + c4) * 4 + 8) = o2;
        }
    }
}
__global__ __launch_bounds__(256) void mlpfull_kernel(
    const void* q, const void* W1, const void* b1, const void* W2, const void* b2,
    u16* xcf4, int n_atoms, const int* flag)
{
    if (*flag) mlpfull_body<true >(q, W1, b1, W2, b2, xcf4, n_atoms);
    else       mlpfull_body<false>(q, W1, b1, W2, b2, xcf4, n_atoms);
}

// ---------------------------------------------------------------------------
// CSR build: count -> scan -> scatter perm  (proven)
// ---------------------------------------------------------------------------
__global__ __launch_bounds__(256) void count_kernel(
    const int* __restrict__ idx_i, int* __restrict__ counts, int E)
{
    int e = blockIdx.x * 256 + threadIdx.x;
    if (e < E) atomicAdd(&counts[idx_i[e]], 1);
}

__global__ __launch_bounds__(1024) void scan_kernel(
    const int* __restrict__ counts, int* __restrict__ offsets, int n)
{
    __shared__ int buf[1024];
    const int t = threadIdx.x;
    const int m = (n + 1023) >> 10;
    const int i0 = t * m;
    int s = 0;
    for (int r = 0; r < m; ++r) {
        int i = i0 + r;
        if (i < n) s += counts[i];
    }
    buf[t] = s;
    __syncthreads();
    for (int off = 1; off < 1024; off <<= 1) {
        int add = (t >= off) ? buf[t - off] : 0;
        __syncthreads();
        buf[t] += add;
        __syncthreads();
    }
    int run = buf[t] - s;
    for (int r = 0; r < m; ++r) {
        int i = i0 + r;
        if (i < n) { offsets[i] = run; run += counts[i]; }
    }
    if (t == 1023) offsets[n] = buf[1023];
}

__global__ __launch_bounds__(256) void scatter_kernel(
    const int* __restrict__ idx_i, const int* __restrict__ offsets,
    int* __restrict__ cursor, int* __restrict__ perm, int E)
{
    int e = blockIdx.x * 256 + threadIdx.x;
    if (e < E) {
        int i = idx_i[e];
        int pos = offsets[i] + atomicAdd(&cursor[i], 1);
        perm[pos] = e;
    }
}

// ---------------------------------------------------------------------------
// FUSED gather, interleaved operands: per edge per lane only 5 VMEM:
//   3x Wij (nontemporal dwordx2), 1x uint4 xcf4, 1x uint4 mubf4; dir via shfl.
// ---------------------------------------------------------------------------
template<bool BF>
__device__ void gfused_body(const void* q, const void* mu, const void* Wij,
                            const void* dir, const u16* __restrict__ xcf4,
                            const u16* __restrict__ mubf4,
                            const int* __restrict__ idx_j,
                            const int* __restrict__ offsets,
                            const int* __restrict__ perm,
                            void* out, int n_atoms, int E)
{
    int a    = blockIdx.x * 4 + (threadIdx.x >> 6);
    int lane = threadIdx.x & 63;
    if (a >= n_atoms) return;
    const size_t fo = 2 * lane;
    const size_t ob = (size_t)n_atoms * F;

    float2 sq = LD2<BF>(q, (size_t)a * F + fo);
    float2 s0 = LD2<BF>(mu, (size_t)a * F3 + fo);
    float2 s1 = LD2<BF>(mu, (size_t)a * F3 + 128 + fo);
    float2 s2 = LD2<BF>(mu, (size_t)a * F3 + 256 + fo);

    int k0 = offsets[a], k1 = offsets[a + 1];
    for (int kb = k0; kb < k1; kb += 64) {
        int cnt = k1 - kb; if (cnt > 64) cnt = 64;
        int e_r = 0, j_r = 0;
        float d0_r = 0.0f, d1_r = 0.0f, d2_r = 0.0f;
        if (lane < cnt) {
            e_r = perm[kb + lane]; if ((unsigned)e_r >= (unsigned)E) e_r = 0;
            j_r = idx_j[e_r];      if ((unsigned)j_r >= (unsigned)n_atoms) j_r = 0;
            d0_r = LD<BF>(dir, (size_t)e_r * 3 + 0);
            d1_r = LD<BF>(dir, (size_t)e_r * 3 + 1);
            d2_r = LD<BF>(dir, (size_t)e_r * 3 + 2);
        }
#pragma unroll 4
        for (int c = 0; c < cnt; ++c) {
            int   e  = __shfl(e_r, c, 64);
            int   j  = __shfl(j_r, c, 64);
            float d0 = __shfl(d0_r, c, 64);
            float d1 = __shfl(d1_r, c, 64);
            float d2 = __shfl(d2_r, c, 64);

            float2 wq = NTLD2<BF>(Wij, (size_t)e * F3 + fo);
            float2 wR = NTLD2<BF>(Wij, (size_t)e * F3 + 128 + fo);
            float2 wm = NTLD2<BF>(Wij, (size_t)e * F3 + 256 + fo);
            uint4 xv = *(const uint4*)(xcf4  + (size_t)j * 512 + 8 * (size_t)lane);
            uint4 mv = *(const uint4*)(mubf4 + (size_t)j * 512 + 8 * (size_t)lane);

            float xq0 = bf2f((u16)(xv.x & 0xffff)), xR0 = bf2f((u16)(xv.x >> 16));
            float xm0 = bf2f((u16)(xv.y & 0xffff));
            float xq1 = bf2f((u16)(xv.z & 0xffff)), xR1 = bf2f((u16)(xv.z >> 16));
            float xm1 = bf2f((u16)(xv.w & 0xffff));
            float m00 = bf2f((u16)(mv.x & 0xffff)), m01 = bf2f((u16)(mv.x >> 16));
            float m02 = bf2f((u16)(mv.y & 0xffff));
            float m10 = bf2f((u16)(mv.z & 0xffff)), m11 = bf2f((u16)(mv.z >> 16));
            float m12 = bf2f((u16)(mv.w & 0xffff));

            sq.x += wq.x * xq0;  sq.y += wq.y * xq1;
            float tR0 = wR.x * xR0, tR1 = wR.y * xR1;
            float tm0 = wm.x * xm0, tm1 = wm.y * xm1;
            s0.x += tR0 * d0 + tm0 * m00;  s0.y += tR1 * d0 + tm1 * m10;
            s1.x += tR0 * d1 + tm0 * m01;  s1.y += tR1 * d1 + tm1 * m11;
            s2.x += tR0 * d2 + tm0 * m02;  s2.y += tR1 * d2 + tm1 * m12;
        }
    }
    NTST2<BF>(out, (size_t)a * F + fo, sq);
    NTST2<BF>(out, ob + (size_t)a * F3 + fo,       s0);
    NTST2<BF>(out, ob + (size_t)a * F3 + 128 + fo, s1);
    NTST2<BF>(out, ob + (size_t)a * F3 + 256 + fo, s2);
}
__global__ __launch_bounds__(256) void gfused_kernel(
    const void* q, const void* mu, const void* Wij, const void* dir,
    const u16* xcf4, const u16* mubf4, const int* idx_j, const int* offsets,
    const int* perm, void* out, int n_atoms, int E, const int* flag)
{
    if (*flag) gfused_body<true >(q, mu, Wij, dir, xcf4, mubf4, idx_j, offsets, perm, out, n_atoms, E);
    else       gfused_body<false>(q, mu, Wij, dir, xcf4, mubf4, idx_j, offsets, perm, out, n_atoms, E);
}

// ---------------------------------------------------------------------------
// Fallback path (proven round-4): chunked MLP + chunked gathers
// ---------------------------------------------------------------------------
template<bool BF>
__device__ void mlp_body(const void* q, const void* W1, const void* b1,
                         const void* W2, const void* b2,
                         u16* __restrict__ xc, u16* __restrict__ hbuf,
                         int cb, int mode, int n_atoms)
{
    __shared__ float qT[F][PAD];
    __shared__ float hT[F][PAD];

    const int tid = threadIdx.x;
    const int a0  = blockIdx.x * TA;
    const int c4  = (tid & 31) * 4;
    const int r4  = (tid >> 5) * 4;

    if (mode == 2) {
        for (int i = tid; i < TA * F / 8; i += 256) {
            int a = i >> 4, f0 = (i & 15) * 8;
            float4 v0, v1;
            if (a0 + a < n_atoms) {
                v0 = LD4<true>(hbuf, (size_t)(a0 + a) * F + f0);
                v1 = LD4<true>(hbuf, (size_t)(a0 + a) * F + f0 + 4);
            } else { v0 = v1 = make_float4(0, 0, 0, 0); }
            hT[f0 + 0][a] = v0.x; hT[f0 + 1][a] = v0.y; hT[f0 + 2][a] = v0.z; hT[f0 + 3][a] = v0.w;
            hT[f0 + 4][a] = v1.x; hT[f0 + 5][a] = v1.y; hT[f0 + 6][a] = v1.z; hT[f0 + 7][a] = v1.w;
        }
        __syncthreads();
    } else {
        for (int i = tid; i < TA * F / 8; i += 256) {
            int a = i >> 4, f0 = (i & 15) * 8;
            float4 v0, v1;
            if (a0 + a < n_atoms) {
                v0 = LD4<BF>(q, (size_t)(a0 + a) * F + f0);
                v1 = LD4<BF>(q, (size_t)(a0 + a) * F + f0 + 4);
            } else { v0 = v1 = make_float4(0, 0, 0, 0); }
            qT[f0 + 0][a] = v0.x; qT[f0 + 1][a] = v0.y; qT[f0 + 2][a] = v0.z; qT[f0 + 3][a] = v0.w;
            qT[f0 + 4][a] = v1.x; qT[f0 + 5][a] = v1.y; qT[f0 + 6][a] = v1.z; qT[f0 + 7][a] = v1.w;
        }
        __syncthreads();

        float acc[4][4];
#pragma unroll
        for (int rr = 0; rr < 4; ++rr)
#pragma unroll
            for (int cc = 0; cc < 4; ++cc) acc[rr][cc] = 0.0f;

        for (int f = 0; f < F; ++f) {
            float4 qv = *(const float4*)&qT[f][r4];
            float4 w  = LD4<BF>(W1, (size_t)f * F + c4);
            float qa[4] = {qv.x, qv.y, qv.z, qv.w};
            float wa[4] = {w.x, w.y, w.z, w.w};
#pragma unroll
            for (int rr = 0; rr < 4; ++rr)
#pragma unroll
                for (int cc = 0; cc < 4; ++cc)
                    acc[rr][cc] += qa[rr] * wa[cc];
        }
        float hv[4][4];
#pragma unroll
        for (int cc = 0; cc < 4; ++cc) {
            float bb = LD<BF>(b1, c4 + cc);
#pragma unroll
            for (int rr = 0; rr < 4; ++rr) {
                float h = acc[rr][cc] + bb;
                float s = h / (1.0f + __expf(-h));
                hv[rr][cc] = s;
                hT[c4 + cc][r4 + rr] = s;
            }
        }
        if (mode == 1) {
#pragma unroll
            for (int rr = 0; rr < 4; ++rr) {
                int ga = a0 + r4 + rr;
                if (ga < n_atoms) {
                    *(u32*)(hbuf + (size_t)ga * F + c4)     = ((u32)f2bf(hv[rr][1]) << 16) | f2bf(hv[rr][0]);
                    *(u32*)(hbuf + (size_t)ga * F + c4 + 2) = ((u32)f2bf(hv[rr][3]) << 16) | f2bf(hv[rr][2]);
                }
            }
        }
        __syncthreads();
    }

    float acc[4][4];
#pragma unroll
    for (int rr = 0; rr < 4; ++rr)
#pragma unroll
        for (int cc = 0; cc < 4; ++cc) acc[rr][cc] = 0.0f;

    for (int f = 0; f < F; ++f) {
        float4 hv = *(const float4*)&hT[f][r4];
        float4 w  = LD4<BF>(W2, (size_t)f * F3 + cb * F + c4);
        float ha[4] = {hv.x, hv.y, hv.z, hv.w};
        float wa[4] = {w.x, w.y, w.z, w.w};
#pragma unroll
        for (int rr = 0; rr < 4; ++rr)
#pragma unroll
            for (int cc = 0; cc < 4; ++cc)
                acc[rr][cc] += ha[rr] * wa[cc];
    }
    float bb[4];
#pragma unroll
    for (int cc = 0; cc < 4; ++cc) bb[cc] = LD<BF>(b2, cb * F + c4 + cc);
#pragma unroll
    for (int rr = 0; rr < 4; ++rr) {
        int ga = a0 + r4 + rr;
        if (ga < n_atoms) {
            *(u32*)(xc + (size_t)ga * F + c4)     = ((u32)f2bf(acc[rr][1] + bb[1]) << 16) | f2bf(acc[rr][0] + bb[0]);
            *(u32*)(xc + (size_t)ga * F + c4 + 2) = ((u32)f2bf(acc[rr][3] + bb[3]) << 16) | f2bf(acc[rr][2] + bb[2]);
        }
    }
}
__global__ __launch_bounds__(256) void mlp_kernel(
    const void* q, const void* W1, const void* b1, const void* W2, const void* b2,
    u16* xc, u16* hbuf, int cb, int mode, int n_atoms, const int* flag)
{
    if (*flag) mlp_body<true >(q, W1, b1, W2, b2, xc, hbuf, cb, mode, n_atoms);
    else       mlp_body<false>(q, W1, b1, W2, b2, xc, hbuf, cb, mode, n_atoms);
}

template<bool BF>
__device__ void gq_body(const void* q, const void* Wij, const u16* __restrict__ xc,
                        const int* __restrict__ idx_j, const int* __restrict__ offsets,
                        const int* __restrict__ perm, void* out, int n_atoms, int E)
{
    int a    = blockIdx.x * 4 + (threadIdx.x >> 6);
    int lane = threadIdx.x & 63;
    if (a >= n_atoms) return;
    const size_t fo = 2 * lane;

    float2 s = LD2<BF>(q, (size_t)a * F + fo);
    int k0 = offsets[a], k1 = offsets[a + 1];
    for (int kb = k0; kb < k1; kb += 64) {
        int cnt = k1 - kb; if (cnt > 64) cnt = 64;
        int e_r = 0, j_r = 0;
        if (lane < cnt) {
            e_r = perm[kb + lane]; if ((unsigned)e_r >= (unsigned)E) e_r = 0;
            j_r = idx_j[e_r];      if ((unsigned)j_r >= (unsigned)n_atoms) j_r = 0;
        }
        for (int c = 0; c < cnt; ++c) {
            int e = __shfl(e_r, c, 64);
            int j = __shfl(j_r, c, 64);
            float2 w  = LD2<BF>(Wij, (size_t)e * F3 + fo);
            float2 xv = LD2bf(xc, (size_t)j * F + fo);
            s.x += w.x * xv.x;
            s.y += w.y * xv.y;
        }
    }
    ST2<BF>(out, (size_t)a * F + fo, s);
}
__global__ __launch_bounds__(256) void gather_q_kernel(
    const void* q, const void* Wij, const u16* xc, const int* idx_j,
    const int* offsets, const int* perm, void* out, int n_atoms, int E, const int* flag)
{
    if (*flag) gq_body<true >(q, Wij, xc, idx_j, offsets, perm, out, n_atoms, E);
    else       gq_body<false>(q, Wij, xc, idx_j, offsets, perm, out, n_atoms, E);
}

template<bool BF, int MODE>
__device__ void gmu_body(const void* mu, const void* Wij, const void* dir,
                         const u16* __restrict__ xc, const int* __restrict__ idx_j,
                         const int* __restrict__ offsets, const int* __restrict__ perm,
                         void* out, int n_atoms, int E)
{
    int a    = blockIdx.x * 4 + (threadIdx.x >> 6);
    int lane = threadIdx.x & 63;
    if (a >= n_atoms) return;
    const size_t fo = 2 * lane;
    const size_t ob = (size_t)n_atoms * F;

    float2 s0, s1, s2;
    if (MODE == 1) {
        s0 = LD2<BF>(mu, (size_t)a * F3 + fo);
        s1 = LD2<BF>(mu, (size_t)a * F3 + 128 + fo);
        s2 = LD2<BF>(mu, (size_t)a * F3 + 256 + fo);
    } else {
        s0 = LD2<BF>(out, ob + (size_t)a * F3 + fo);
        s1 = LD2<BF>(out, ob + (size_t)a * F3 + 128 + fo);
        s2 = LD2<BF>(out, ob + (size_t)a * F3 + 256 + fo);
    }

    const int wofs = (MODE == 1) ? 128 : 256;
    int k0 = offsets[a], k1 = offsets[a + 1];
    for (int kb = k0; kb < k1; kb += 64) {
        int cnt = k1 - kb; if (cnt > 64) cnt = 64;
        int e_r = 0, j_r = 0;
        if (lane < cnt) {
            e_r = perm[kb + lane]; if ((unsigned)e_r >= (unsigned)E) e_r = 0;
            j_r = idx_j[e_r];      if ((unsigned)j_r >= (unsigned)n_atoms) j_r = 0;
        }
        for (int c = 0; c < cnt; ++c) {
            int e = __shfl(e_r, c, 64);
            int j = __shfl(j_r, c, 64);
            float2 w  = LD2<BF>(Wij, (size_t)e * F3 + wofs + fo);
            float2 xv = LD2bf(xc, (size_t)j * F + fo);
            float wx0 = w.x * xv.x, wx1 = w.y * xv.y;
            if (MODE == 1) {
                float d0 = LD<BF>(dir, (size_t)e * 3 + 0);
                float d1 = LD<BF>(dir, (size_t)e * 3 + 1);
                float d2 = LD<BF>(dir, (size_t)e * 3 + 2);
                s0.x += wx0 * d0; s0.y += wx1 * d0;
                s1.x += wx0 * d1; s1.y += wx1 * d1;
                s2.x += wx0 * d2; s2.y += wx1 * d2;
            } else {
                float2 m0 = LD2<BF>(mu, (size_t)j * F3 + fo);
                float2 m1 = LD2<BF>(mu, (size_t)j * F3 + 128 + fo);
                float2 m2 = LD2<BF>(mu, (size_t)j * F3 + 256 + fo);
                s0.x += wx0 * m0.x; s0.y += wx1 * m0.y;
                s1.x += wx0 * m1.x; s1.y += wx1 * m1.y;
                s2.x += wx0 * m2.x; s2.y += wx1 * m2.y;
            }
        }
    }
    ST2<BF>(out, ob + (size_t)a * F3 + fo,       s0);
    ST2<BF>(out, ob + (size_t)a * F3 + 128 + fo, s1);
    ST2<BF>(out, ob + (size_t)a * F3 + 256 + fo, s2);
}
__global__ __launch_bounds__(256) void gather_mu_kernel(
    const void* mu, const void* Wij, const void* dir, const u16* xc,
    const int* idx_j, const int* offsets, const int* perm, void* out,
    int n_atoms, int E, int mode, const int* flag)
{
    if (*flag) {
        if (mode == 1) gmu_body<true, 1>(mu, Wij, dir, xc, idx_j, offsets, perm, out, n_atoms, E);
        else           gmu_body<true, 2>(mu, Wij, dir, xc, idx_j, offsets, perm, out, n_atoms, E);
    } else {
        if (mode == 1) gmu_body<false, 1>(mu, Wij, dir, xc, idx_j, offsets, perm, out, n_atoms, E);
        else           gmu_body<false, 2>(mu, Wij, dir, xc, idx_j, offsets, perm, out, n_atoms, E);
    }
}

// ---------------------------------------------------------------------------
extern "C" void kernel_launch(void* const* d_in, const int* in_sizes, int n_in,
                              void* d_out, int out_size, void* d_ws, size_t ws_size,
                              hipStream_t stream)
{
    const void* q   = d_in[0];
    const void* mu  = d_in[1];
    const void* Wij = d_in[2];
    const void* dir = d_in[3];
    const void* W1  = d_in[4];
    const void* b1  = d_in[5];
    const void* W2  = d_in[6];
    const void* b2  = d_in[7];
    const int* idx_i = (const int*)d_in[8];
    const int* idx_j = (const int*)d_in[9];

    const int n_atoms = in_sizes[0] / F;        // 50000
    const int E       = in_sizes[8];            // 500000
    const int eBlocks = (E + 255) / 256;
    const int gBlocks = (n_atoms + 3) / 4;
    const int mlpBlocks = (n_atoms + TA - 1) / TA;

    // FULL layout (~108 MB): xcf4 u16[A*128*4] | mubf4 u16[A*128*4] | flag[4]
    //                        | counts[A] | cursor[A] | offsets[A+1] | perm[E]
    {
        u16* xcf4    = (u16*)d_ws;
        u16* mubf4   = xcf4 + (size_t)n_atoms * F * 4;
        int* flag    = (int*)(mubf4 + (size_t)n_atoms * F * 4);
        int* counts  = flag + 4;
        int* cursor  = counts + n_atoms;
        int* offsets = cursor + n_atoms;
        int* perm    = offsets + n_atoms + 1;
        size_t need  = (size_t)((char*)(perm + E) - (char*)d_ws);

        if (ws_size >= need) {
            detect_kernel<<<1, 256, 0, stream>>>(q, flag);
            hipMemsetAsync(counts, 0, (size_t)2 * n_atoms * sizeof(int), stream);
            count_kernel<<<eBlocks, 256, 0, stream>>>(idx_i, counts, E);
            scan_kernel<<<1, 1024, 0, stream>>>(counts, offsets, n_atoms);
            scatter_kernel<<<eBlocks, 256, 0, stream>>>(idx_i, offsets, cursor, perm, E);

            mu4_kernel<<<(n_atoms + 1) / 2, 256, 0, stream>>>(mu, mubf4, n_atoms, flag);
            mlpfull_kernel<<<mlpBlocks, 256, 0, stream>>>(q, W1, b1, W2, b2, xcf4, n_atoms, flag);

            gfused_kernel<<<gBlocks, 256, 0, stream>>>(q, mu, Wij, dir, xcf4, mubf4,
                                                       idx_j, offsets, perm, d_out,
                                                       n_atoms, E, flag);
            return;
        }
    }

    // FALLBACK (proven round-4 path)
    u16* xc      = (u16*)d_ws;
    int* flag    = (int*)(xc + (size_t)n_atoms * F);
    int* counts  = flag + 4;
    int* cursor  = counts + n_atoms;
    int* offsets = cursor + n_atoms;
    int* perm    = offsets + n_atoms + 1;
    u16* hbuf    = (u16*)(perm + E);
    size_t need_h = (size_t)((char*)(hbuf + (size_t)n_atoms * F) - (char*)d_ws);
    const bool useH = (ws_size >= need_h);

    detect_kernel<<<1, 256, 0, stream>>>(q, flag);
    hipMemsetAsync(counts, 0, (size_t)2 * n_atoms * sizeof(int), stream);
    count_kernel<<<eBlocks, 256, 0, stream>>>(idx_i, counts, E);
    scan_kernel<<<1, 1024, 0, stream>>>(counts, offsets, n_atoms);
    scatter_kernel<<<eBlocks, 256, 0, stream>>>(idx_i, offsets, cursor, perm, E);

    mlp_kernel<<<mlpBlocks, 256, 0, stream>>>(q, W1, b1, W2, b2, xc, hbuf, 0,
                                              useH ? 1 : 0, n_atoms, flag);
    gather_q_kernel<<<gBlocks, 256, 0, stream>>>(q, Wij, xc, idx_j, offsets, perm,
                                                 d_out, n_atoms, E, flag);
    mlp_kernel<<<mlpBlocks, 256, 0, stream>>>(q, W1, b1, W2, b2, xc, hbuf, 1,
                                              useH ? 2 : 0, n_atoms, flag);
    gather_mu_kernel<<<gBlocks, 256, 0, stream>>>(mu, Wij, dir, xc, idx_j, offsets, perm,
                                                  d_out, n_atoms, E, 1, flag);
    mlp_kernel<<<mlpBlocks, 256, 0, stream>>>(q, W1, b1, W2, b2, xc, hbuf, 2,
                                              useH ? 2 : 0, n_atoms, flag);
    gather_mu_kernel<<<gBlocks, 256, 0, stream>>>(mu, Wij, dir, xc, idx_j, offsets, perm,
                                                  d_out, n_atoms, E, 2, flag);
}

// Round 7
// 586.096 us; speedup vs baseline: 1.0377x; 1.0377x over previous
//
#include <hip/hip_runtime.h>

typedef unsigned short u16;
typedef unsigned int   u32;
typedef unsigned long long u64;

#define F 128
#define F3 384
#define TA 32          // atoms per MLP block
#define PAD 36         // padded LDS row (floats)
#define ROW 768        // xm12 row length in u16 (1536 B): 64 pairs x 12

__device__ __forceinline__ float bf2f(u16 v) {
    union { u32 u; float f; } c; c.u = ((u32)v) << 16; return c.f;
}
__device__ __forceinline__ u16 f2bf(float f) {
    union { float fv; u32 u; } c; c.fv = f;
    u32 u = c.u;
    return (u16)((u + 0x7fffu + ((u >> 16) & 1u)) >> 16);   // round-nearest-even
}
__device__ __forceinline__ float u2f(u32 v) {
    union { u32 u; float f; } c; c.u = v; return c.f;
}
__device__ __forceinline__ u32 f2u(float v) {
    union { float f; u32 u; } c; c.f = v; return c.u;
}
__device__ __forceinline__ u32 pk(float a, float b) {
    return ((u32)f2bf(b) << 16) | f2bf(a);
}

// dtype-generic accessors: BF=true -> bf16 (u16) arrays, false -> f32 arrays
template<bool BF> __device__ __forceinline__ float LD(const void* p, size_t i) {
    return BF ? bf2f(((const u16*)p)[i]) : ((const float*)p)[i];
}
template<bool BF> __device__ __forceinline__ float2 LD2(const void* p, size_t i) {
    if (BF) {
        u32 v = *(const u32*)((const u16*)p + i);
        float2 r; r.x = bf2f((u16)(v & 0xffff)); r.y = bf2f((u16)(v >> 16)); return r;
    }
    return *(const float2*)((const float*)p + i);
}
template<bool BF> __device__ __forceinline__ void ST2(void* p, size_t i, float2 v) {
    if (BF) { *(u32*)((u16*)p + i) = pk(v.x, v.y); }
    else    { *(float2*)((float*)p + i) = v; }
}
__device__ __forceinline__ float2 LD2bf(const u16* p, size_t i) {
    u32 v = *(const u32*)(p + i);
    float2 r; r.x = bf2f((u16)(v & 0xffff)); r.y = bf2f((u16)(v >> 16)); return r;
}
template<bool BF> __device__ __forceinline__ float4 LD4(const void* p, size_t i) {
    if (BF) {
        uint2 v = *(const uint2*)((const u16*)p + i);
        float4 r;
        r.x = bf2f((u16)(v.x & 0xffff)); r.y = bf2f((u16)(v.x >> 16));
        r.z = bf2f((u16)(v.y & 0xffff)); r.w = bf2f((u16)(v.y >> 16));
        return r;
    }
    return *(const float4*)((const float*)p + i);
}
// nontemporal variants (touch-once streams: Wij, out)
template<bool BF> __device__ __forceinline__ float2 NTLD2(const void* p, size_t i) {
    if (BF) {
        u32 v = __builtin_nontemporal_load((const u32*)((const u16*)p + i));
        float2 r; r.x = bf2f((u16)(v & 0xffff)); r.y = bf2f((u16)(v >> 16)); return r;
    } else {
        u64 v = __builtin_nontemporal_load((const u64*)((const float*)p + i));
        float2 r; r.x = u2f((u32)v); r.y = u2f((u32)(v >> 32)); return r;
    }
}
template<bool BF> __device__ __forceinline__ void NTST2(void* p, size_t i, float2 v) {
    if (BF) {
        u32 o = pk(v.x, v.y);
        __builtin_nontemporal_store(o, (u32*)((u16*)p + i));
    } else {
        u64 o = ((u64)f2u(v.y) << 32) | f2u(v.x);
        __builtin_nontemporal_store(o, (u64*)((float*)p + i));
    }
}

// ---------------------------------------------------------------------------
// Dtype detector (proven)
// ---------------------------------------------------------------------------
__global__ __launch_bounds__(256) void detect_kernel(const void* q, int* flag) {
    __shared__ int cnt;
    if (threadIdx.x == 0) cnt = 0;
    __syncthreads();
    const u16* p = (const u16*)q;
    int c = 0;
    for (int i = threadIdx.x; i < 1024; i += 256) {
        u16 v = p[2 * i];
        int e = (v >> 7) & 0xFF;
        if (e >= 100 && e <= 150) c++;
    }
    atomicAdd(&cnt, c);
    __syncthreads();
    if (threadIdx.x == 0) *flag = (cnt > 512) ? 1 : 0;
}

// ---------------------------------------------------------------------------
// mu -> packed half of xm12: entries [6..11] of each 12-u16 pair-block
// thread owns one feature PAIR of one atom (64 threads/atom, 4 atoms/block)
// ---------------------------------------------------------------------------
template<bool BF>
__device__ void mu12_body(const void* mu, u16* xm12, int n_atoms) {
    int a = blockIdx.x * 4 + (threadIdx.x >> 6);
    int p = threadIdx.x & 63;
    if (a >= n_atoms) return;
    float2 m0 = LD2<BF>(mu, (size_t)a * F3 + 2 * p);
    float2 m1 = LD2<BF>(mu, (size_t)a * F3 + 128 + 2 * p);
    float2 m2 = LD2<BF>(mu, (size_t)a * F3 + 256 + 2 * p);
    u16* base = xm12 + (size_t)a * ROW + p * 12;
    *(u32*)(base + 6) = pk(m0.x, m0.y);                 // byte off 12: 4-aligned
    *(uint2*)(base + 8) = make_uint2(pk(m1.x, m1.y), pk(m2.x, m2.y)); // byte 16: 8-aligned
}
__global__ __launch_bounds__(256) void mu12_kernel(const void* mu, u16* xm12,
                                                   int n_atoms, const int* flag) {
    if (*flag) mu12_body<true >(mu, xm12, n_atoms);
    else       mu12_body<false>(mu, xm12, n_atoms);
}

// ---------------------------------------------------------------------------
// Full MLP -> packed half of xm12: entries [0..5] (xq,xR,xm) of each pair-block
// ---------------------------------------------------------------------------
template<bool BF>
__device__ void mlpfull_body(const void* q, const void* W1, const void* b1,
                             const void* W2, const void* b2,
                             u16* __restrict__ xm12, int n_atoms)
{
    __shared__ float qT[F][PAD];
    __shared__ float hT[F][PAD];

    const int tid = threadIdx.x;
    const int a0  = blockIdx.x * TA;
    const int c4  = (tid & 31) * 4;
    const int r4  = (tid >> 5) * 4;

    for (int i = tid; i < TA * F / 8; i += 256) {
        int a = i >> 4, f0 = (i & 15) * 8;
        float4 v0, v1;
        if (a0 + a < n_atoms) {
            v0 = LD4<BF>(q, (size_t)(a0 + a) * F + f0);
            v1 = LD4<BF>(q, (size_t)(a0 + a) * F + f0 + 4);
        } else { v0 = v1 = make_float4(0, 0, 0, 0); }
        qT[f0 + 0][a] = v0.x; qT[f0 + 1][a] = v0.y; qT[f0 + 2][a] = v0.z; qT[f0 + 3][a] = v0.w;
        qT[f0 + 4][a] = v1.x; qT[f0 + 5][a] = v1.y; qT[f0 + 6][a] = v1.z; qT[f0 + 7][a] = v1.w;
    }
    __syncthreads();

    // phase 1: h = silu(q@W1 + b1)
    {
        float acc[4][4];
#pragma unroll
        for (int rr = 0; rr < 4; ++rr)
#pragma unroll
            for (int cc = 0; cc < 4; ++cc) acc[rr][cc] = 0.0f;

        for (int f = 0; f < F; ++f) {
            float4 qv = *(const float4*)&qT[f][r4];
            float4 w  = LD4<BF>(W1, (size_t)f * F + c4);
            float qa[4] = {qv.x, qv.y, qv.z, qv.w};
            float wa[4] = {w.x, w.y, w.z, w.w};
#pragma unroll
            for (int rr = 0; rr < 4; ++rr)
#pragma unroll
                for (int cc = 0; cc < 4; ++cc)
                    acc[rr][cc] += qa[rr] * wa[cc];
        }
#pragma unroll
        for (int cc = 0; cc < 4; ++cc) {
            float bb = LD<BF>(b1, c4 + cc);
#pragma unroll
            for (int rr = 0; rr < 4; ++rr) {
                float h = acc[rr][cc] + bb;
                hT[c4 + cc][r4 + rr] = h / (1.0f + __expf(-h));
            }
        }
    }
    __syncthreads();

    // phase 2: all 3 chunks, register-staged; then packed stores
    float xout[4][4][3];   // [rr][feat cc][chunk cb]
#pragma unroll
    for (int cb = 0; cb < 3; ++cb) {
        float acc[4][4];
#pragma unroll
        for (int rr = 0; rr < 4; ++rr)
#pragma unroll
            for (int cc = 0; cc < 4; ++cc) acc[rr][cc] = 0.0f;

        for (int f = 0; f < F; ++f) {
            float4 hv = *(const float4*)&hT[f][r4];
            float4 w  = LD4<BF>(W2, (size_t)f * F3 + cb * F + c4);
            float ha[4] = {hv.x, hv.y, hv.z, hv.w};
            float wa[4] = {w.x, w.y, w.z, w.w};
#pragma unroll
            for (int rr = 0; rr < 4; ++rr)
#pragma unroll
                for (int cc = 0; cc < 4; ++cc)
                    acc[rr][cc] += ha[rr] * wa[cc];
        }
#pragma unroll
        for (int cc = 0; cc < 4; ++cc) {
            float bb = LD<BF>(b2, cb * F + c4 + cc);
#pragma unroll
            for (int rr = 0; rr < 4; ++rr)
                xout[rr][cc][cb] = acc[rr][cc] + bb;
        }
    }
#pragma unroll
    for (int rr = 0; rr < 4; ++rr) {
        int ga = a0 + r4 + rr;
        if (ga < n_atoms) {
            // pairs p0 = c4/2 (features c4,c4+1 -> cc 0,1), p0+1 (cc 2,3)
            int p0 = c4 >> 1;
            u16* b0 = xm12 + (size_t)ga * ROW + p0 * 12;
            *(uint2*)(b0) = make_uint2(pk(xout[rr][0][0], xout[rr][1][0]),
                                       pk(xout[rr][0][1], xout[rr][1][1]));
            *(u32*)(b0 + 4) = pk(xout[rr][0][2], xout[rr][1][2]);
            u16* b1p = b0 + 12;
            *(uint2*)(b1p) = make_uint2(pk(xout[rr][2][0], xout[rr][3][0]),
                                        pk(xout[rr][2][1], xout[rr][3][1]));
            *(u32*)(b1p + 4) = pk(xout[rr][2][2], xout[rr][3][2]);
        }
    }
}
__global__ __launch_bounds__(256) void mlpfull_kernel(
    const void* q, const void* W1, const void* b1, const void* W2, const void* b2,
    u16* xm12, int n_atoms, const int* flag)
{
    if (*flag) mlpfull_body<true >(q, W1, b1, W2, b2, xm12, n_atoms);
    else       mlpfull_body<false>(q, W1, b1, W2, b2, xm12, n_atoms);
}

// ---------------------------------------------------------------------------
// CSR build: count -> scan -> scatter (ej4 = {e, j, dir01_bf16, dir2_bf16})
// ---------------------------------------------------------------------------
__global__ __launch_bounds__(256) void count_kernel(
    const int* __restrict__ idx_i, int* __restrict__ counts, int E)
{
    int e = blockIdx.x * 256 + threadIdx.x;
    if (e < E) atomicAdd(&counts[idx_i[e]], 1);
}

__global__ __launch_bounds__(1024) void scan_kernel(
    const int* __restrict__ counts, int* __restrict__ offsets, int n)
{
    __shared__ int buf[1024];
    const int t = threadIdx.x;
    const int m = (n + 1023) >> 10;
    const int i0 = t * m;
    int s = 0;
    for (int r = 0; r < m; ++r) {
        int i = i0 + r;
        if (i < n) s += counts[i];
    }
    buf[t] = s;
    __syncthreads();
    for (int off = 1; off < 1024; off <<= 1) {
        int add = (t >= off) ? buf[t - off] : 0;
        __syncthreads();
        buf[t] += add;
        __syncthreads();
    }
    int run = buf[t] - s;
    for (int r = 0; r < m; ++r) {
        int i = i0 + r;
        if (i < n) { offsets[i] = run; run += counts[i]; }
    }
    if (t == 1023) offsets[n] = buf[1023];
}

template<bool BF>
__device__ void scatter_body(const int* __restrict__ idx_i, const int* __restrict__ idx_j,
                             const void* __restrict__ dir, const int* __restrict__ offsets,
                             int* __restrict__ cursor, int4* __restrict__ ej4, int E)
{
    int e = blockIdx.x * 256 + threadIdx.x;
    if (e < E) {
        int i = idx_i[e];
        int pos = offsets[i] + atomicAdd(&cursor[i], 1);
        float d0 = LD<BF>(dir, (size_t)e * 3 + 0);
        float d1 = LD<BF>(dir, (size_t)e * 3 + 1);
        float d2 = LD<BF>(dir, (size_t)e * 3 + 2);
        int4 v;
        v.x = e;
        v.y = idx_j[e];
        v.z = (int)pk(d0, d1);
        v.w = (int)(u32)f2bf(d2);
        ej4[pos] = v;
    }
}
__global__ __launch_bounds__(256) void scatter_kernel(
    const int* idx_i, const int* idx_j, const void* dir, const int* offsets,
    int* cursor, int4* ej4, int E, const int* flag)
{
    if (*flag) scatter_body<true >(idx_i, idx_j, dir, offsets, cursor, ej4, E);
    else       scatter_body<false>(idx_i, idx_j, dir, offsets, cursor, ej4, E);
}

// ---------------------------------------------------------------------------
// FUSED gather: per edge per lane: 3x NT Wij (8B) + 3x uint2 from ONE packed
// xm12 row (1536 B contiguous). Staging: one int4 per edge; 4 shfl/edge.
// ---------------------------------------------------------------------------
template<bool BF>
__device__ void gfused_body(const void* q, const void* mu, const void* Wij,
                            const u16* __restrict__ xm12,
                            const int4* __restrict__ ej4,
                            const int* __restrict__ offsets,
                            void* out, int n_atoms, int E)
{
    int a    = blockIdx.x * 4 + (threadIdx.x >> 6);
    int lane = threadIdx.x & 63;
    if (a >= n_atoms) return;
    const size_t fo = 2 * lane;
    const size_t ob = (size_t)n_atoms * F;

    float2 sq = LD2<BF>(q, (size_t)a * F + fo);
    float2 s0 = LD2<BF>(mu, (size_t)a * F3 + fo);
    float2 s1 = LD2<BF>(mu, (size_t)a * F3 + 128 + fo);
    float2 s2 = LD2<BF>(mu, (size_t)a * F3 + 256 + fo);

    int k0 = offsets[a], k1 = offsets[a + 1];
    for (int kb = k0; kb < k1; kb += 64) {
        int cnt = k1 - kb; if (cnt > 64) cnt = 64;
        int e_r = 0, j_r = 0, d01_r = 0, d2_r = 0;
        if (lane < cnt) {
            int4 t = ej4[kb + lane];
            e_r = t.x; if ((unsigned)e_r >= (unsigned)E) e_r = 0;
            j_r = t.y; if ((unsigned)j_r >= (unsigned)n_atoms) j_r = 0;
            d01_r = t.z; d2_r = t.w;
        }
#pragma unroll 4
        for (int c = 0; c < cnt; ++c) {
            int e   = __shfl(e_r, c, 64);
            int j   = __shfl(j_r, c, 64);
            int d01 = __shfl(d01_r, c, 64);
            int d2i = __shfl(d2_r, c, 64);
            float d0 = bf2f((u16)((u32)d01 & 0xffff));
            float d1 = bf2f((u16)((u32)d01 >> 16));
            float d2 = bf2f((u16)((u32)d2i & 0xffff));

            float2 wq = NTLD2<BF>(Wij, (size_t)e * F3 + fo);
            float2 wR = NTLD2<BF>(Wij, (size_t)e * F3 + 128 + fo);
            float2 wm = NTLD2<BF>(Wij, (size_t)e * F3 + 256 + fo);

            const u16* row = xm12 + (size_t)j * ROW + lane * 12;
            uint2 v0 = *(const uint2*)(row);        // xq pair, xR pair
            uint2 v1 = *(const uint2*)(row + 4);    // xm pair, m0 pair
            uint2 v2 = *(const uint2*)(row + 8);    // m1 pair, m2 pair

            float xq0 = bf2f((u16)(v0.x & 0xffff)), xq1 = bf2f((u16)(v0.x >> 16));
            float xR0 = bf2f((u16)(v0.y & 0xffff)), xR1 = bf2f((u16)(v0.y >> 16));
            float xm0 = bf2f((u16)(v1.x & 0xffff)), xm1 = bf2f((u16)(v1.x >> 16));
            float m00 = bf2f((u16)(v1.y & 0xffff)), m01 = bf2f((u16)(v1.y >> 16));
            float m10 = bf2f((u16)(v2.x & 0xffff)), m11 = bf2f((u16)(v2.x >> 16));
            float m20 = bf2f((u16)(v2.y & 0xffff)), m21 = bf2f((u16)(v2.y >> 16));

            sq.x += wq.x * xq0;  sq.y += wq.y * xq1;
            float tR0 = wR.x * xR0, tR1 = wR.y * xR1;
            float tm0 = wm.x * xm0, tm1 = wm.y * xm1;
            s0.x += tR0 * d0 + tm0 * m00;  s0.y += tR1 * d0 + tm1 * m01;
            s1.x += tR0 * d1 + tm0 * m10;  s1.y += tR1 * d1 + tm1 * m11;
            s2.x += tR0 * d2 + tm0 * m20;  s2.y += tR1 * d2 + tm1 * m21;
        }
    }
    NTST2<BF>(out, (size_t)a * F + fo, sq);
    NTST2<BF>(out, ob + (size_t)a * F3 + fo,       s0);
    NTST2<BF>(out, ob + (size_t)a * F3 + 128 + fo, s1);
    NTST2<BF>(out, ob + (size_t)a * F3 + 256 + fo, s2);
}
__global__ __launch_bounds__(256) void gfused_kernel(
    const void* q, const void* mu, const void* Wij,
    const u16* xm12, const int4* ej4, const int* offsets,
    void* out, int n_atoms, int E, const int* flag)
{
    if (*flag) gfused_body<true >(q, mu, Wij, xm12, ej4, offsets, out, n_atoms, E);
    else       gfused_body<false>(q, mu, Wij, xm12, ej4, offsets, out, n_atoms, E);
}

// ---------------------------------------------------------------------------
extern "C" void kernel_launch(void* const* d_in, const int* in_sizes, int n_in,
                              void* d_out, int out_size, void* d_ws, size_t ws_size,
                              hipStream_t stream)
{
    const void* q   = d_in[0];
    const void* mu  = d_in[1];
    const void* Wij = d_in[2];
    const void* dir = d_in[3];
    const void* W1  = d_in[4];
    const void* b1  = d_in[5];
    const void* W2  = d_in[6];
    const void* b2  = d_in[7];
    const int* idx_i = (const int*)d_in[8];
    const int* idx_j = (const int*)d_in[9];

    const int n_atoms = in_sizes[0] / F;        // 50000
    const int E       = in_sizes[8];            // 500000
    const int eBlocks   = (E + 255) / 256;
    const int gBlocks   = (n_atoms + 3) / 4;
    const int mlpBlocks = (n_atoms + TA - 1) / TA;

    // ws layout (~90 MB; ws is ~3 GB per round-4/5 WRITE_SIZE evidence):
    //   xm12 u16[A*768] | flag[4] | counts[A] | cursor[A] | offsets[A+1] | ej4 int4[E]
    u16*  xm12    = (u16*)d_ws;
    int*  flag    = (int*)(xm12 + (size_t)n_atoms * ROW);
    int*  counts  = flag + 4;
    int*  cursor  = counts + n_atoms;
    int*  offsets = cursor + n_atoms;
    int4* ej4     = (int4*)(((size_t)(offsets + n_atoms + 1) + 15) & ~(size_t)15);

    detect_kernel<<<1, 256, 0, stream>>>(q, flag);
    hipMemsetAsync(counts, 0, (size_t)2 * n_atoms * sizeof(int), stream);
    count_kernel<<<eBlocks, 256, 0, stream>>>(idx_i, counts, E);
    scan_kernel<<<1, 1024, 0, stream>>>(counts, offsets, n_atoms);
    scatter_kernel<<<eBlocks, 256, 0, stream>>>(idx_i, idx_j, dir, offsets,
                                                cursor, ej4, E, flag);

    mu12_kernel<<<gBlocks, 256, 0, stream>>>(mu, xm12, n_atoms, flag);
    mlpfull_kernel<<<mlpBlocks, 256, 0, stream>>>(q, W1, b1, W2, b2, xm12, n_atoms, flag);

    gfused_kernel<<<gBlocks, 256, 0, stream>>>(q, mu, Wij, xm12, ej4, offsets,
                                               d_out, n_atoms, E, flag);
}